// Round 6
// baseline (3630.604 us; speedup 1.0000x reference)
//
#include <hip/hip_runtime.h>
#include <hip/hip_bf16.h>
#include <math.h>

// LorentzTemporalBlock — bf16 MFMA GEMMs + analytically-simplified elementwise.
// B=8,T=512,J=26,D=256,H=8,DH=32,HID=1024. R = 106496 rows (= 416*256).
// Identities: t = LN(xs); u2 = LN(xs + sinh(|o|)/|o| * o)  (LN scale-invariance).
// R3: 8-phase 256x256 MFMA GEMM (T2+T3/T4+T5): 802 us.
// R4: BJT layout; k_kv v2 (per-(bj,h) blocks) — NULL: occupancy 10%.
// R5: k_kv v3 (global_load_lds staging) — PATHOLOGICAL: 2.9GB fetch/3.3GB
//     write per dispatch (22x/120x amplification), 2883 us. Mechanism in the
//     lds-DMA path; not the algorithm (block streams are contiguous+disjoint).
// R6: k_kv v4 — same (bj, 128-t chunk) decomposition, staging reverted to the
//     verified plain pattern: per-thread s16x8 loads -> ds_write_b128 ->
//     __syncthreads; next-chunk reg prefetch before compute. No inline asm.

#define EPSF 1e-6f
#define B_ 8
#define T_ 512
#define J_ 26
#define D_ 256
#define H_ 8
#define DH_ 32
#define HID_ 1024
#define NP1 257
#define R_ (B_*T_*J_)    // 106496
#define NBJ (B_*J_)      // 208
#define NBH (NBJ*H_)     // 1664

typedef float  f32x4  __attribute__((ext_vector_type(4)));
typedef short  s16x8  __attribute__((ext_vector_type(8)));
typedef short  s16x4  __attribute__((ext_vector_type(4)));

// r' = (b*26+j)*512 + t  ->  r = (b*512+t)*26 + j   (wave-uniform div by const)
__device__ __forceinline__ int rp_to_r(int rp) {
  int bj = rp >> 9, t = rp & 511;
  int b = bj / 26, j = bj - 26 * b;
  return (b * 512 + t) * 26 + j;
}

// ---------- async global->LDS 16B (dst = uniform base + lane*16) ----------
__device__ __forceinline__ void async16(const void* g, void* l) {
  __builtin_amdgcn_global_load_lds(
      (const __attribute__((address_space(1))) unsigned int*)g,
      (__attribute__((address_space(3))) unsigned int*)l, 16, 0, 0);
}

// ---------- wave-wide (64 lane) sum, result in all lanes ----------
__device__ __forceinline__ float wave_sum(float v) {
#pragma unroll
  for (int m = 32; m; m >>= 1) v += __shfl_xor(v, m, 64);
  return v;
}

// ---------- weight transpose+convert: W fp32 [K][N] -> Wt bf16 [N][K] ----------
__global__ __launch_bounds__(256) void k_wconv(const float* __restrict__ W,
                                               __hip_bfloat16* __restrict__ Wt,
                                               int K, int N) {
  __shared__ float tile[32][33];
  int n0 = blockIdx.x * 32, k0 = blockIdx.y * 32;
  int tx = threadIdx.x, ty = threadIdx.y;   // (32,8)
#pragma unroll
  for (int i = ty; i < 32; i += 8) tile[i][tx] = W[(size_t)(k0 + i) * N + n0 + tx];
  __syncthreads();
#pragma unroll
  for (int i = ty; i < 32; i += 8)
    Wt[(size_t)(n0 + i) * K + k0 + tx] = __float2bfloat16(tile[tx][i]);
}

// ---------- t = LN(xs): read x row r, write t row r'  (wave-per-row) ----------
__global__ __launch_bounds__(256) void k_t(const float* __restrict__ x,
                                           const float* __restrict__ g1,
                                           const float* __restrict__ beta1,
                                           __hip_bfloat16* __restrict__ t) {
  int rp = blockIdx.x * 4 + (threadIdx.x >> 6);
  int l = threadIdx.x & 63;
  int r = rp_to_r(rp);
  const float* xr = x + (size_t)r * NP1;
  float xs[4];
#pragma unroll
  for (int i = 0; i < 4; ++i) xs[i] = xr[1 + l + 64*i];
  float p1 = xs[0]+xs[1]+xs[2]+xs[3];
  float p2 = xs[0]*xs[0]+xs[1]*xs[1]+xs[2]*xs[2]+xs[3]*xs[3];
  float s1 = wave_sum(p1);
  float s2 = wave_sum(p2);
  float mean = s1 * (1.0f/256.0f);
  float var = s2 * (1.0f/256.0f) - mean*mean;
  float rstd = rsqrtf(var + 1e-5f);
#pragma unroll
  for (int i = 0; i < 4; ++i) {
    int c = l + 64*i;
    t[(size_t)rp * D_ + c] = __float2bfloat16((xs[i]-mean)*rstd*g1[c] + beta1[c]);
  }
}

// ---------- 256x256 8-phase bf16 MFMA GEMM: C = act(A @ Bt^T + bias) ----------
// (verified in R3 — unchanged)
#define PHASE(BUF, MH, NH, GIDX, DO_VM) {                                      \
    s16x8 af_[4][2]; s16x8 bf_[2][2];                                          \
    const char* ab_ = lds + ((BUF)*2+(MH))*16384;                              \
    const char* bb_ = lds + 65536 + ((BUF)*2+(NH))*16384;                      \
    _Pragma("unroll") for (int f_ = 0; f_ < 4; ++f_)                           \
      _Pragma("unroll") for (int ks_ = 0; ks_ < 2; ++ks_)                      \
        af_[f_][ks_] = *(const s16x8*)(ab_ + aoffs[f_][ks_]);                  \
    _Pragma("unroll") for (int ni_ = 0; ni_ < 2; ++ni_)                        \
      _Pragma("unroll") for (int ks_ = 0; ks_ < 2; ++ks_)                      \
        bf_[ni_][ks_] = *(const s16x8*)(bb_ + boffs[ni_][ks_]);                \
    STAGE_HALF((GIDX) + 6);                                                    \
    if (DO_VM) asm volatile("s_waitcnt vmcnt(4)" ::: "memory");                \
    asm volatile("s_barrier" ::: "memory");                                    \
    __builtin_amdgcn_sched_barrier(0);                                         \
    __builtin_amdgcn_s_setprio(1);                                             \
    _Pragma("unroll") for (int ks_ = 0; ks_ < 2; ++ks_)                        \
      _Pragma("unroll") for (int f_ = 0; f_ < 4; ++f_)                         \
        _Pragma("unroll") for (int ni_ = 0; ni_ < 2; ++ni_)                    \
          acc[(MH)*4+f_][(NH)*2+ni_] = __builtin_amdgcn_mfma_f32_16x16x32_bf16(\
              bf_[ni_][ks_], af_[f_][ks_], acc[(MH)*4+f_][(NH)*2+ni_], 0,0,0); \
    __builtin_amdgcn_s_setprio(0);                                             \
    asm volatile("s_barrier" ::: "memory");                                    \
  }

template<int ACT, int OUTF, int KDIM>
__global__ __launch_bounds__(512, 2) void k_gemm(const __hip_bfloat16* __restrict__ A,
                                                 const __hip_bfloat16* __restrict__ Bt,
                                                 const float* __restrict__ bias,
                                                 void* __restrict__ Cout,
                                                 int M, int N) {
  extern __shared__ char lds[];
  constexpr int NKT = KDIM / 64;
  int tid = threadIdx.x;
  int w = tid >> 6, l = tid & 63;
  int wr = w >> 2, wc = w & 3;
  int ml = l & 15, quad = l >> 4;
  int n0 = blockIdx.x * 256, m0 = blockIdx.y * 256;

  const short* Ag = (const short*)A + (size_t)m0 * KDIM;
  const short* Bg = (const short*)Bt + (size_t)n0 * KDIM;

  int srow = w*8 + (l >> 3);
  int scol = (((l & 7) ^ ((l >> 3) & 7)) * 8);

  auto STAGE_HALF = [&](int n) {
    if (n >= 4*NKT) return;
    int kt = n >> 2;
    int isB = n & 1, h = (n >> 1) & 1, buf = kt & 1;
    const short* src = isB ? Bg : Ag;
    const short* g0 = src + (size_t)(h*128 + srow) * KDIM + kt*64 + scol;
    char* dst = lds + isB*65536 + (buf*2 + h)*16384 + w*1024;
    async16(g0, dst);
    async16(g0 + (size_t)64 * KDIM, dst + 8192);
  };

  int aoffs[4][2], boffs[2][2];
#pragma unroll
  for (int f = 0; f < 4; ++f) {
    int r = wr*64 + f*16 + ml;
#pragma unroll
    for (int ks = 0; ks < 2; ++ks)
      aoffs[f][ks] = (r*128 + ks*64 + quad*16) ^ ((ml & 7) << 4);
  }
#pragma unroll
  for (int ni = 0; ni < 2; ++ni) {
    int rb = wc*32 + ni*16 + ml;
#pragma unroll
    for (int ks = 0; ks < 2; ++ks)
      boffs[ni][ks] = (rb*128 + ks*64 + quad*16) ^ ((ml & 7) << 4);
  }

  f32x4 acc[8][4];
#pragma unroll
  for (int i = 0; i < 8; ++i)
#pragma unroll
    for (int j = 0; j < 4; ++j) acc[i][j] = {0.f, 0.f, 0.f, 0.f};

#pragma unroll
  for (int n = 0; n < 6; ++n) STAGE_HALF(n);
  asm volatile("s_waitcnt vmcnt(4)" ::: "memory");
  asm volatile("s_barrier" ::: "memory");

  for (int cc = 0; cc < NKT/2; ++cc) {
    int g0 = cc * 8;
    PHASE(0, 0, 0, g0+0, 0)
    PHASE(0, 0, 1, g0+1, 0)
    PHASE(0, 1, 0, g0+2, 0)
    PHASE(0, 1, 1, g0+3, 1)
    PHASE(1, 0, 0, g0+4, 0)
    PHASE(1, 0, 1, g0+5, 0)
    PHASE(1, 1, 0, g0+6, 0)
    PHASE(1, 1, 1, g0+7, 1)
  }

#pragma unroll
  for (int mi = 0; mi < 8; ++mi) {
    size_t row = (size_t)(m0 + (mi>>2)*128 + wr*64 + (mi&3)*16 + ml);
#pragma unroll
    for (int nj = 0; nj < 4; ++nj) {
      int col = n0 + (nj>>1)*128 + wc*32 + (nj&1)*16 + quad*4;
      f32x4 bj = *(const f32x4*)&bias[col];
      f32x4 v = acc[mi][nj] + bj;
      if (ACT == 1) {
#pragma unroll
        for (int e = 0; e < 4; ++e) v[e] = (v[e] > 0.0f) ? v[e] + 1.0f : __expf(v[e]);
      } else if (ACT == 2) {
#pragma unroll
        for (int e = 0; e < 4; ++e) {
          float vv = v[e], v2 = vv * vv;
          float ex = __expf(vv * fmaf(v2, -0.0713548327f, -1.5957691216f));
          v[e] = vv * __builtin_amdgcn_rcpf(1.0f + ex);
        }
      }
      if (OUTF) {
        *(f32x4*)&((float*)Cout)[row * N + col] = v;
      } else {
        s16x4 sv;
#pragma unroll
        for (int e = 0; e < 4; ++e) {
          __hip_bfloat16 b = __float2bfloat16(v[e]);
          sv[e] = *(short*)&b;
        }
        *(s16x4*)&((__hip_bfloat16*)Cout)[row * N + col] = sv;
      }
    }
  }
}

// ---------- kv + ksum partials per (bj, 128-t chunk) — v4 ----------
// grid (4, 208), 512 threads = 8 waves; wave w = head w.
// Chunk = 32 t of full 256-col rows, single LDS buffer (32KB), plain staging:
// per-thread 32B s16x8 loads (coalesced) -> ds_write_b128 -> __syncthreads;
// next-chunk loads issued into regs before compute (latency hides under FMA).
// Lane l: kg=l>>3, dg=l&7; acc[m][n] = sum_t pk[t][kg*4+m] * v[t][dg*4+n].
// Per t: 2 broadcast ds_read_b64 (8 distinct addrs x 8-lane bcast, no conflict).
__global__ __launch_bounds__(512) void k_kv(const __hip_bfloat16* __restrict__ pk,
                                            const __hip_bfloat16* __restrict__ v,
                                            float* __restrict__ kv_part,
                                            float* __restrict__ ks_part) {
  __shared__ short spk[32*256];   // 16KB: row t at t*256, head w cols [w*32,+32)
  __shared__ short sv [32*256];   // 16KB
  int tc = blockIdx.x, bj = blockIdx.y;
  int tid = threadIdx.x;
  int w = tid >> 6, l = tid & 63;
  int kg = l >> 3, dg = l & 7;

  const short* pkg = (const short*)pk + ((size_t)bj*512 + tc*128) * 256 + tid*16;
  const short* vg  = (const short*)v  + ((size_t)bj*512 + tc*128) * 256 + tid*16;

  s16x8 rp0, rp1, rv0, rv1;
  auto GLOAD = [&](int c) {
    const short* p = pkg + c*8192;
    const short* q = vg  + c*8192;
    rp0 = *(const s16x8*)(p);
    rp1 = *(const s16x8*)(p + 8);
    rv0 = *(const s16x8*)(q);
    rv1 = *(const s16x8*)(q + 8);
  };

  f32x4 acc[4] = {{0,0,0,0},{0,0,0,0},{0,0,0,0},{0,0,0,0}};  // acc[m][n]
  float ks[4] = {0.f, 0.f, 0.f, 0.f};

  GLOAD(0);
#pragma unroll
  for (int c = 0; c < 4; ++c) {
    *(s16x8*)&spk[tid*16]     = rp0;
    *(s16x8*)&spk[tid*16 + 8] = rp1;
    *(s16x8*)&sv [tid*16]     = rv0;
    *(s16x8*)&sv [tid*16 + 8] = rv1;
    __syncthreads();
    if (c < 3) GLOAD(c + 1);          // in flight during compute
    const short* pb = &spk[w*32 + kg*4];
    const short* vb = &sv [w*32 + dg*4];
#pragma unroll
    for (int t = 0; t < 32; ++t) {
      s16x4 pa = *(const s16x4*)(pb + t*256);
      s16x4 va = *(const s16x4*)(vb + t*256);
      float pf[4], vf[4];
#pragma unroll
      for (int e = 0; e < 4; ++e) {
        pf[e] = __uint_as_float(((unsigned)(unsigned short)pa[e]) << 16);
        vf[e] = __uint_as_float(((unsigned)(unsigned short)va[e]) << 16);
      }
#pragma unroll
      for (int m = 0; m < 4; ++m) {
#pragma unroll
        for (int n = 0; n < 4; ++n) acc[m][n] = fmaf(pf[m], vf[n], acc[m][n]);
        ks[m] += pf[m];
      }
    }
    __syncthreads();                  // reads done before next chunk's writes
  }

  // partial writes: kv_part[(tc*NBH + bj*8+w)*1024 + k*32 + d]
  float* kvp = kv_part + ((size_t)tc*NBH + bj*8 + w) * 1024;
#pragma unroll
  for (int m = 0; m < 4; ++m)
    *(f32x4*)&kvp[(kg*4 + m)*32 + dg*4] = acc[m];
  if (dg == 0) {
    float* ksp = ks_part + ((size_t)tc*NBH + bj*8 + w) * 32;
#pragma unroll
    for (int m = 0; m < 4; ++m) ksp[kg*4 + m] = ks[m];
  }
}

// ---------- reduce 4 t-partials -> kv, ksum ----------
__global__ __launch_bounds__(256) void k_red(const float* __restrict__ kv_part,
                                             const float* __restrict__ ks_part,
                                             float* __restrict__ kv,
                                             float* __restrict__ ksum) {
  int blk = blockIdx.x, tid = threadIdx.x;
  size_t i = (size_t)blk*1024 + tid*4;
  f32x4 s = {0.f, 0.f, 0.f, 0.f};
#pragma unroll
  for (int tc = 0; tc < 4; ++tc)
    s += *(const f32x4*)&kv_part[(size_t)tc*NBH*1024 + i];
  *(f32x4*)&kv[i] = s;
  if (tid < 32) {
    float ss = 0.f;
#pragma unroll
    for (int tc = 0; tc < 4; ++tc)
      ss += ks_part[(size_t)tc*NBH*32 + (size_t)blk*32 + tid];
    ksum[(size_t)blk*32 + tid] = ss;
  }
}

// ---------- attn = (pq @ kv) / (pq @ ksum + eps) -> bf16  (BJT layout) ----------
__global__ __launch_bounds__(256) void k_attn(const __hip_bfloat16* __restrict__ pq,
                                              const float* __restrict__ kv,
                                              const float* __restrict__ ksum,
                                              __hip_bfloat16* __restrict__ attn) {
  __shared__ float psf[32][264];
  __shared__ float dens[32][8];
  int bj = blockIdx.y;
  int t0 = blockIdx.x * 32;
  int g0 = bj * 512 + t0;        // r' base row
  int tid = threadIdx.x, w = tid >> 6, l = tid & 63;
  int h = w*2 + (l >> 5), dd = l & 31;

  const float* kvp = kv + ((size_t)bj * 8 + h) * (DH_*DH_);
  float kvreg[32];
#pragma unroll
  for (int k = 0; k < 32; ++k) kvreg[k] = kvp[k*32 + dd];

  for (int tr = 0; tr < 32; ++tr)
    psf[tr][tid] = __bfloat162float(pq[(size_t)(g0 + tr) * D_ + tid]);
  __syncthreads();

  {
    int tr = tid & 31, hh = tid >> 5;
    const float* ksp = ksum + ((size_t)bj * 8 + hh) * DH_;
    float dsum = 0.f;
#pragma unroll
    for (int k = 0; k < 32; ++k) dsum = fmaf(psf[tr][hh*32 + k], ksp[k], dsum);
    dens[tr][hh] = dsum;
  }
  __syncthreads();

  for (int tr = 0; tr < 32; ++tr) {
    const float* pr = &psf[tr][h*32];
    float num = 0.f;
#pragma unroll
    for (int k = 0; k < 32; ++k) num = fmaf(pr[k], kvreg[k], num);
    float rden = __builtin_amdgcn_rcpf(dens[tr][h] + EPSF);
    attn[(size_t)(g0 + tr) * D_ + tid] = __float2bfloat16(num * rden);
  }
}

// ---------- u2 = LN(xs + sinh(|o|)/|o| * o): o row r', x row r ----------
__global__ __launch_bounds__(256) void k_u2(const __hip_bfloat16* __restrict__ o,
                                            const float* __restrict__ x,
                                            const float* __restrict__ g2,
                                            const float* __restrict__ beta2,
                                            __hip_bfloat16* __restrict__ u2) {
  int rp = blockIdx.x * 4 + (threadIdx.x >> 6);
  int l = threadIdx.x & 63;
  int r = rp_to_r(rp);
  const float* xr = x + (size_t)r * NP1;
  float ov[4], xs[4];
#pragma unroll
  for (int i = 0; i < 4; ++i) {
    ov[i] = __bfloat162float(o[(size_t)rp * D_ + l + 64*i]);
    xs[i] = xr[1 + l + 64*i];
  }
  float p2 = ov[0]*ov[0]+ov[1]*ov[1]+ov[2]*ov[2]+ov[3]*ov[3];
  float s2o = wave_sum(p2);
  float no = fmaxf(sqrtf(s2o), EPSF);
  float e = __expf(no);
  float c = (e - 1.0f/e) * 0.5f / no;
  float mi[4];
#pragma unroll
  for (int i = 0; i < 4; ++i) mi[i] = xs[i] + c * ov[i];
  float q1 = mi[0]+mi[1]+mi[2]+mi[3];
  float q2 = mi[0]*mi[0]+mi[1]*mi[1]+mi[2]*mi[2]+mi[3]*mi[3];
  float s1 = wave_sum(q1);
  float s2 = wave_sum(q2);
  float mean = s1 * (1.0f/256.0f);
  float var = s2 * (1.0f/256.0f) - mean*mean;
  float rstd = rsqrtf(var + 1e-5f);
#pragma unroll
  for (int i = 0; i < 4; ++i) {
    int cc = l + 64*i;
    u2[(size_t)rp * D_ + cc] = __float2bfloat16((mi[i]-mean)*rstd*g2[cc] + beta2[cc]);
  }
}

// ---------- out = expmap0(f): f row r', out row r ----------
__global__ __launch_bounds__(256) void k_out(const float* __restrict__ f,
                                             float* __restrict__ out) {
  int rp = blockIdx.x * 4 + (threadIdx.x >> 6);
  int l = threadIdx.x & 63;
  int r = rp_to_r(rp);
  const float* fr = f + (size_t)rp * D_;
  float fv[4];
#pragma unroll
  for (int i = 0; i < 4; ++i) fv[i] = fr[l + 64*i];
  float p2 = fv[0]*fv[0]+fv[1]*fv[1]+fv[2]*fv[2]+fv[3]*fv[3];
  float s2 = wave_sum(p2);
  float n = fmaxf(sqrtf(s2), EPSF);
  float e = __expf(n);
  float ie = 1.0f / e;
  float sh = (e - ie) * 0.5f;
  float ch = (e + ie) * 0.5f;
  float s = sh / n;
  float* orow = out + (size_t)r * NP1;
  if (l == 0) orow[0] = ch;
#pragma unroll
  for (int i = 0; i < 4; ++i) orow[1 + l + 64*i] = s * fv[i];
}

extern "C" void kernel_launch(void* const* d_in, const int* in_sizes, int n_in,
                              void* d_out, int out_size, void* d_ws, size_t ws_size,
                              hipStream_t stream) {
  const float* x     = (const float*)d_in[0];
  const float* g1    = (const float*)d_in[1];
  const float* beta1 = (const float*)d_in[2];
  const float* Wq    = (const float*)d_in[3];
  const float* Wk    = (const float*)d_in[4];
  const float* Wv    = (const float*)d_in[5];
  const float* Wo    = (const float*)d_in[6];
  const float* bq    = (const float*)d_in[7];
  const float* bk    = (const float*)d_in[8];
  const float* bv    = (const float*)d_in[9];
  const float* bo    = (const float*)d_in[10];
  const float* g2    = (const float*)d_in[11];
  const float* beta2 = (const float*)d_in[12];
  const float* W1    = (const float*)d_in[13];
  const float* bf1   = (const float*)d_in[14];
  const float* W2    = (const float*)d_in[15];
  const float* bf2   = (const float*)d_in[16];
  float* out = (float*)d_out;
  char* ws = (char*)d_ws;

  // ---- workspace layout (bytes) ----
  size_t off = 0;
  __hip_bfloat16* wqT = (__hip_bfloat16*)(ws + off); off += (size_t)D_*D_*2;
  __hip_bfloat16* wkT = (__hip_bfloat16*)(ws + off); off += (size_t)D_*D_*2;
  __hip_bfloat16* wvT = (__hip_bfloat16*)(ws + off); off += (size_t)D_*D_*2;
  __hip_bfloat16* woT = (__hip_bfloat16*)(ws + off); off += (size_t)D_*D_*2;
  __hip_bfloat16* w1T = (__hip_bfloat16*)(ws + off); off += (size_t)HID_*D_*2;
  __hip_bfloat16* w2T = (__hip_bfloat16*)(ws + off); off += (size_t)D_*HID_*2;
  float* kvb = (float*)(ws + off); off += (size_t)NBH*(DH_*DH_)*4;
  float* ksb = (float*)(ws + off); off += (size_t)NBH*DH_*4;
  off = (off + 255) & ~(size_t)255;
  __hip_bfloat16* tb = (__hip_bfloat16*)(ws + off); off += (size_t)R_*D_*2;
  __hip_bfloat16* qb = (__hip_bfloat16*)(ws + off); off += (size_t)R_*D_*2;
  __hip_bfloat16* kb = (__hip_bfloat16*)(ws + off); off += (size_t)R_*D_*2;
  __hip_bfloat16* vb = (__hip_bfloat16*)(ws + off); off += (size_t)R_*D_*2;
  __hip_bfloat16* hid = (__hip_bfloat16*)(ws + off); off += (size_t)(R_/2)*HID_*2;
  float* fbuf = (float*)qb;   // fp32 R*256 aliases qb+kb (both consumed by then)
  // kv/ksum partials alias hid (dead until the MLP): 4*1664*1024*4 = 27.3MB + 0.9MB
  float* kv_part = (float*)hid;
  float* ks_part = kv_part + (size_t)4*NBH*1024;

  static bool attr_done = false;
  if (!attr_done) {
    hipFuncSetAttribute((const void*)k_gemm<1,0,256>,  hipFuncAttributeMaxDynamicSharedMemorySize, 131072);
    hipFuncSetAttribute((const void*)k_gemm<0,0,256>,  hipFuncAttributeMaxDynamicSharedMemorySize, 131072);
    hipFuncSetAttribute((const void*)k_gemm<2,0,256>,  hipFuncAttributeMaxDynamicSharedMemorySize, 131072);
    hipFuncSetAttribute((const void*)k_gemm<0,1,1024>, hipFuncAttributeMaxDynamicSharedMemorySize, 131072);
    attr_done = true;
  }

  dim3 tconv(32, 8);
  k_wconv<<<dim3(D_/32,  D_/32),  tconv, 0, stream>>>(Wq, wqT, D_,  D_);
  k_wconv<<<dim3(D_/32,  D_/32),  tconv, 0, stream>>>(Wk, wkT, D_,  D_);
  k_wconv<<<dim3(D_/32,  D_/32),  tconv, 0, stream>>>(Wv, wvT, D_,  D_);
  k_wconv<<<dim3(D_/32,  D_/32),  tconv, 0, stream>>>(Wo, woT, D_,  D_);
  k_wconv<<<dim3(HID_/32, D_/32), tconv, 0, stream>>>(W1, w1T, D_,  HID_);
  k_wconv<<<dim3(D_/32, HID_/32), tconv, 0, stream>>>(W2, w2T, HID_, D_);

  k_t<<<R_/4, 256, 0, stream>>>(x, g1, beta1, tb);      // tb in r' layout

  dim3 gqkv(D_/256, R_/256);                 // (1, 416)
  k_gemm<1,0,256><<<gqkv, 512, 131072, stream>>>(tb, wqT, bq, qb, R_, D_);
  k_gemm<1,0,256><<<gqkv, 512, 131072, stream>>>(tb, wkT, bk, kb, R_, D_);
  k_gemm<0,0,256><<<gqkv, 512, 131072, stream>>>(tb, wvT, bv, vb, R_, D_);

  k_kv<<<dim3(4, NBJ), 512, 0, stream>>>(kb, vb, kv_part, ks_part);
  k_red<<<NBH, 256, 0, stream>>>(kv_part, ks_part, kvb, ksb);
  k_attn<<<dim3(T_/32, NBJ), 256, 0, stream>>>(qb, kvb, ksb, kb);   // attn -> kb

  k_gemm<0,0,256><<<gqkv, 512, 131072, stream>>>(kb, woT, bo, vb, R_, D_);  // o -> vb (r')
  k_u2<<<R_/4, 256, 0, stream>>>(vb, x, g2, beta2, tb);                     // u2 -> tb (r')

  const int Rc = R_ / 2;                     // 53248 rows per MLP chunk
  for (int c = 0; c < 2; ++c) {
    k_gemm<2,0,256><<<dim3(HID_/256, Rc/256), 512, 131072, stream>>>(
        tb + (size_t)c * Rc * D_, w1T, bf1, hid, Rc, HID_);
    k_gemm<0,1,1024><<<dim3(D_/256, Rc/256), 512, 131072, stream>>>(
        hid, w2T, bf2, fbuf + (size_t)c * Rc * D_, Rc, D_);
  }

  k_out<<<R_/4, 256, 0, stream>>>(fbuf, out);
}

// Round 7
// 782.218 us; speedup vs baseline: 4.6414x; 4.6414x over previous
//
#include <hip/hip_runtime.h>
#include <hip/hip_bf16.h>
#include <math.h>

// LorentzTemporalBlock — bf16 MFMA GEMMs + analytically-simplified elementwise.
// B=8,T=512,J=26,D=256,H=8,DH=32,HID=1024. R = 106496 rows (= 416*256).
// Identities: t = LN(xs); u2 = LN(xs + sinh(|o|)/|o| * o)  (LN scale-invariance).
// R3: 8-phase 256x256 MFMA GEMM (T2+T3/T4+T5): 802 us.
// R5/R6: k_kv t-split partial variants (512-thr blocks, partials aliased into
//     hid) — PATHOLOGICAL 100x write amplification with BOTH lds-DMA and plain
//     staging; mechanism unidentified. Reverted to the v1-proven granularity.
// R7: k_kv v5 — one block per (bj,h) (grid 1664, 256 thr), direct kvb/ksb
//     writes, no partials/aliasing/reduce. 32-row chunks, vectorized 8B
//     global loads + f32 LDS + reg prefetch (v1 structure, 4x fewer barriers).
//     k_out fused into W2 GEMM epilogue (EPI=2): quad-shuffle + 4KB LDS
//     cross-wave row-norm reduce, writes expmap0 directly to out. fbuf gone.

#define EPSF 1e-6f
#define B_ 8
#define T_ 512
#define J_ 26
#define D_ 256
#define H_ 8
#define DH_ 32
#define HID_ 1024
#define NP1 257
#define R_ (B_*T_*J_)    // 106496
#define NBJ (B_*J_)      // 208
#define NBH (NBJ*H_)     // 1664

typedef float  f32x4  __attribute__((ext_vector_type(4)));
typedef short  s16x8  __attribute__((ext_vector_type(8)));
typedef short  s16x4  __attribute__((ext_vector_type(4)));

// r' = (b*26+j)*512 + t  ->  r = (b*512+t)*26 + j   (wave-uniform div by const)
__device__ __forceinline__ int rp_to_r(int rp) {
  int bj = rp >> 9, t = rp & 511;
  int b = bj / 26, j = bj - 26 * b;
  return (b * 512 + t) * 26 + j;
}

// ---------- async global->LDS 16B (dst = uniform base + lane*16) ----------
__device__ __forceinline__ void async16(const void* g, void* l) {
  __builtin_amdgcn_global_load_lds(
      (const __attribute__((address_space(1))) unsigned int*)g,
      (__attribute__((address_space(3))) unsigned int*)l, 16, 0, 0);
}

// ---------- wave-wide (64 lane) sum, result in all lanes ----------
__device__ __forceinline__ float wave_sum(float v) {
#pragma unroll
  for (int m = 32; m; m >>= 1) v += __shfl_xor(v, m, 64);
  return v;
}

// ---------- weight transpose+convert: W fp32 [K][N] -> Wt bf16 [N][K] ----------
__global__ __launch_bounds__(256) void k_wconv(const float* __restrict__ W,
                                               __hip_bfloat16* __restrict__ Wt,
                                               int K, int N) {
  __shared__ float tile[32][33];
  int n0 = blockIdx.x * 32, k0 = blockIdx.y * 32;
  int tx = threadIdx.x, ty = threadIdx.y;   // (32,8)
#pragma unroll
  for (int i = ty; i < 32; i += 8) tile[i][tx] = W[(size_t)(k0 + i) * N + n0 + tx];
  __syncthreads();
#pragma unroll
  for (int i = ty; i < 32; i += 8)
    Wt[(size_t)(n0 + i) * K + k0 + tx] = __float2bfloat16(tile[tx][i]);
}

// ---------- t = LN(xs): read x row r, write t row r'  (wave-per-row) ----------
__global__ __launch_bounds__(256) void k_t(const float* __restrict__ x,
                                           const float* __restrict__ g1,
                                           const float* __restrict__ beta1,
                                           __hip_bfloat16* __restrict__ t) {
  int rp = blockIdx.x * 4 + (threadIdx.x >> 6);
  int l = threadIdx.x & 63;
  int r = rp_to_r(rp);
  const float* xr = x + (size_t)r * NP1;
  float xs[4];
#pragma unroll
  for (int i = 0; i < 4; ++i) xs[i] = xr[1 + l + 64*i];
  float p1 = xs[0]+xs[1]+xs[2]+xs[3];
  float p2 = xs[0]*xs[0]+xs[1]*xs[1]+xs[2]*xs[2]+xs[3]*xs[3];
  float s1 = wave_sum(p1);
  float s2 = wave_sum(p2);
  float mean = s1 * (1.0f/256.0f);
  float var = s2 * (1.0f/256.0f) - mean*mean;
  float rstd = rsqrtf(var + 1e-5f);
#pragma unroll
  for (int i = 0; i < 4; ++i) {
    int c = l + 64*i;
    t[(size_t)rp * D_ + c] = __float2bfloat16((xs[i]-mean)*rstd*g1[c] + beta1[c]);
  }
}

// ---------- 256x256 8-phase bf16 MFMA GEMM: C = act(A @ Bt^T + bias) ----------
// EPI 0: bf16 C store. EPI 2: fused expmap0 -> out (N must be 256, grid.x=1):
//   per-row n2 via quad-shuffle + LDS cross-wave reduce; scalar stores to
//   out[rp_to_r(mOff+row)*257]. (verified R3 main loop — unchanged)
#define PHASE(BUF, MH, NH, GIDX, DO_VM) {                                      \
    s16x8 af_[4][2]; s16x8 bf_[2][2];                                          \
    const char* ab_ = lds + ((BUF)*2+(MH))*16384;                              \
    const char* bb_ = lds + 65536 + ((BUF)*2+(NH))*16384;                      \
    _Pragma("unroll") for (int f_ = 0; f_ < 4; ++f_)                           \
      _Pragma("unroll") for (int ks_ = 0; ks_ < 2; ++ks_)                      \
        af_[f_][ks_] = *(const s16x8*)(ab_ + aoffs[f_][ks_]);                  \
    _Pragma("unroll") for (int ni_ = 0; ni_ < 2; ++ni_)                        \
      _Pragma("unroll") for (int ks_ = 0; ks_ < 2; ++ks_)                      \
        bf_[ni_][ks_] = *(const s16x8*)(bb_ + boffs[ni_][ks_]);                \
    STAGE_HALF((GIDX) + 6);                                                    \
    if (DO_VM) asm volatile("s_waitcnt vmcnt(4)" ::: "memory");                \
    asm volatile("s_barrier" ::: "memory");                                    \
    __builtin_amdgcn_sched_barrier(0);                                         \
    __builtin_amdgcn_s_setprio(1);                                             \
    _Pragma("unroll") for (int ks_ = 0; ks_ < 2; ++ks_)                        \
      _Pragma("unroll") for (int f_ = 0; f_ < 4; ++f_)                         \
        _Pragma("unroll") for (int ni_ = 0; ni_ < 2; ++ni_)                    \
          acc[(MH)*4+f_][(NH)*2+ni_] = __builtin_amdgcn_mfma_f32_16x16x32_bf16(\
              bf_[ni_][ks_], af_[f_][ks_], acc[(MH)*4+f_][(NH)*2+ni_], 0,0,0); \
    __builtin_amdgcn_s_setprio(0);                                             \
    asm volatile("s_barrier" ::: "memory");                                    \
  }

template<int ACT, int EPI, int KDIM>
__global__ __launch_bounds__(512, 2) void k_gemm(const __hip_bfloat16* __restrict__ A,
                                                 const __hip_bfloat16* __restrict__ Bt,
                                                 const float* __restrict__ bias,
                                                 void* __restrict__ Cout,
                                                 int M, int N, int mOff) {
  extern __shared__ char lds[];
  constexpr int NKT = KDIM / 64;
  int tid = threadIdx.x;
  int w = tid >> 6, l = tid & 63;
  int wr = w >> 2, wc = w & 3;
  int ml = l & 15, quad = l >> 4;
  int n0 = blockIdx.x * 256, m0 = blockIdx.y * 256;

  const short* Ag = (const short*)A + (size_t)m0 * KDIM;
  const short* Bg = (const short*)Bt + (size_t)n0 * KDIM;

  int srow = w*8 + (l >> 3);
  int scol = (((l & 7) ^ ((l >> 3) & 7)) * 8);

  auto STAGE_HALF = [&](int n) {
    if (n >= 4*NKT) return;
    int kt = n >> 2;
    int isB = n & 1, h = (n >> 1) & 1, buf = kt & 1;
    const short* src = isB ? Bg : Ag;
    const short* g0 = src + (size_t)(h*128 + srow) * KDIM + kt*64 + scol;
    char* dst = lds + isB*65536 + (buf*2 + h)*16384 + w*1024;
    async16(g0, dst);
    async16(g0 + (size_t)64 * KDIM, dst + 8192);
  };

  int aoffs[4][2], boffs[2][2];
#pragma unroll
  for (int f = 0; f < 4; ++f) {
    int r = wr*64 + f*16 + ml;
#pragma unroll
    for (int ks = 0; ks < 2; ++ks)
      aoffs[f][ks] = (r*128 + ks*64 + quad*16) ^ ((ml & 7) << 4);
  }
#pragma unroll
  for (int ni = 0; ni < 2; ++ni) {
    int rb = wc*32 + ni*16 + ml;
#pragma unroll
    for (int ks = 0; ks < 2; ++ks)
      boffs[ni][ks] = (rb*128 + ks*64 + quad*16) ^ ((ml & 7) << 4);
  }

  f32x4 acc[8][4];
#pragma unroll
  for (int i = 0; i < 8; ++i)
#pragma unroll
    for (int j = 0; j < 4; ++j) acc[i][j] = {0.f, 0.f, 0.f, 0.f};

#pragma unroll
  for (int n = 0; n < 6; ++n) STAGE_HALF(n);
  asm volatile("s_waitcnt vmcnt(4)" ::: "memory");
  asm volatile("s_barrier" ::: "memory");

  for (int cc = 0; cc < NKT/2; ++cc) {
    int g0 = cc * 8;
    PHASE(0, 0, 0, g0+0, 0)
    PHASE(0, 0, 1, g0+1, 0)
    PHASE(0, 1, 0, g0+2, 0)
    PHASE(0, 1, 1, g0+3, 1)
    PHASE(1, 0, 0, g0+4, 0)
    PHASE(1, 0, 1, g0+5, 0)
    PHASE(1, 1, 0, g0+6, 0)
    PHASE(1, 1, 1, g0+7, 1)
  }

  if (EPI == 0) {
#pragma unroll
    for (int mi = 0; mi < 8; ++mi) {
      size_t row = (size_t)(m0 + (mi>>2)*128 + wr*64 + (mi&3)*16 + ml);
#pragma unroll
      for (int nj = 0; nj < 4; ++nj) {
        int col = n0 + (nj>>1)*128 + wc*32 + (nj&1)*16 + quad*4;
        f32x4 bj = *(const f32x4*)&bias[col];
        f32x4 v = acc[mi][nj] + bj;
        if (ACT == 1) {
#pragma unroll
          for (int e = 0; e < 4; ++e) v[e] = (v[e] > 0.0f) ? v[e] + 1.0f : __expf(v[e]);
        } else if (ACT == 2) {
#pragma unroll
          for (int e = 0; e < 4; ++e) {
            float vv = v[e], v2 = vv * vv;
            float ex = __expf(vv * fmaf(v2, -0.0713548327f, -1.5957691216f));
            v[e] = vv * __builtin_amdgcn_rcpf(1.0f + ex);
          }
        }
        s16x4 sv;
#pragma unroll
        for (int e = 0; e < 4; ++e) {
          __hip_bfloat16 b = __float2bfloat16(v[e]);
          sv[e] = *(short*)&b;
        }
        *(s16x4*)&((__hip_bfloat16*)Cout)[row * N + col] = sv;
      }
    }
  } else {
    // EPI==2: out = expmap0(acc + bias), rows mapped r' -> r. N == 256.
    float* out = (float*)Cout;
    float* red = (float*)lds;            // [wr][wc][mi][ml] = 2*4*8*16 floats
    f32x4 bj4[4];
#pragma unroll
    for (int nj = 0; nj < 4; ++nj)
      bj4[nj] = *(const f32x4*)&bias[(nj>>1)*128 + wc*32 + (nj&1)*16 + quad*4];
    float n2[8];
#pragma unroll
    for (int mi = 0; mi < 8; ++mi) {
      float p = 0.f;
#pragma unroll
      for (int nj = 0; nj < 4; ++nj)
#pragma unroll
        for (int e = 0; e < 4; ++e) {
          float f = acc[mi][nj][e] + bj4[nj][e];
          p = fmaf(f, f, p);
        }
      p += __shfl_xor(p, 16, 64);        // sum over quad
      p += __shfl_xor(p, 32, 64);
      n2[mi] = p;
    }
    __syncthreads();                     // main-loop LDS fully retired
    if (quad == 0) {
#pragma unroll
      for (int mi = 0; mi < 8; ++mi)
        red[((wr*4 + wc)*8 + mi)*16 + ml] = n2[mi];
    }
    __syncthreads();
#pragma unroll
    for (int mi = 0; mi < 8; ++mi) {
      float s = 0.f;
#pragma unroll
      for (int w2 = 0; w2 < 4; ++w2)
        s += red[((wr*4 + w2)*8 + mi)*16 + ml];
      n2[mi] = s;
    }
#pragma unroll
    for (int mi = 0; mi < 8; ++mi) {
      int rowp = m0 + (mi>>2)*128 + wr*64 + (mi&3)*16 + ml;
      int r = rp_to_r(mOff + rowp);
      float* orow = out + (size_t)r * NP1;
      float n = fmaxf(sqrtf(n2[mi]), EPSF);
      float e = __expf(n);
      float ie = 1.0f / e;
      float sc = (e - ie) * 0.5f / n;    // sinh(n)/n
      if (wc == 0 && quad == 0) orow[0] = (e + ie) * 0.5f;
#pragma unroll
      for (int nj = 0; nj < 4; ++nj) {
        int col = (nj>>1)*128 + wc*32 + (nj&1)*16 + quad*4;
#pragma unroll
        for (int e2 = 0; e2 < 4; ++e2)
          orow[1 + col + e2] = sc * (acc[mi][nj][e2] + bj4[nj][e2]);
      }
    }
  }
}

// ---------- kv + ksum per (bj,h) — v5: proven granularity, vectorized ----------
// grid NBH (1664 blocks), 256 threads. BJT rows (bj*512+t), cols [h*32,+32).
// 16 chunks of 32 rows: thread (row=tid>>3, cg=tid&7) loads 8B s16x4, cvt,
// ds_write_b128 f32 -> spk/sv[32][32]; reg-prefetch next chunk before compute.
// Compute thread (k0=tid>>5, dd=tid&31): acc[m] += spk[q][k0+8m]*sv[q][dd]
// (broadcast + conflict-free). ksum by wave-0 lanes. Direct kvb/ksb writes.
__global__ __launch_bounds__(256) void k_kv(const __hip_bfloat16* __restrict__ pk,
                                            const __hip_bfloat16* __restrict__ v,
                                            float* __restrict__ kv,
                                            float* __restrict__ ksum) {
  __shared__ float spk[32][32];
  __shared__ float sv [32][32];
  int blk = blockIdx.x;
  int h = blk & 7, bj = blk >> 3;
  int tid = threadIdx.x;
  int row = tid >> 3, cg = tid & 7;
  int k0 = tid >> 5, dd = tid & 31;

  const short* pkg = (const short*)pk + (size_t)bj*512*256 + h*32 + cg*4;
  const short* vg  = (const short*)v  + (size_t)bj*512*256 + h*32 + cg*4;

  s16x4 rp_, rv_;
  auto GLOAD = [&](int c) {
    size_t off = (size_t)(c*32 + row) * 256;
    rp_ = *(const s16x4*)(pkg + off);
    rv_ = *(const s16x4*)(vg + off);
  };

  float acc[4] = {0.f, 0.f, 0.f, 0.f};
  float ks = 0.f;

  GLOAD(0);
  for (int c = 0; c < 16; ++c) {
    f32x4 pf, vf;
#pragma unroll
    for (int e = 0; e < 4; ++e) {
      pf[e] = __uint_as_float(((unsigned)(unsigned short)rp_[e]) << 16);
      vf[e] = __uint_as_float(((unsigned)(unsigned short)rv_[e]) << 16);
    }
    *(f32x4*)&spk[row][cg*4] = pf;
    *(f32x4*)&sv [row][cg*4] = vf;
    __syncthreads();
    if (c < 15) GLOAD(c + 1);           // in flight during compute
#pragma unroll
    for (int q = 0; q < 32; ++q) {
      float vv = sv[q][dd];
#pragma unroll
      for (int m = 0; m < 4; ++m) acc[m] = fmaf(spk[q][k0 + 8*m], vv, acc[m]);
    }
    if (tid < 32) {
#pragma unroll
      for (int q = 0; q < 32; ++q) ks += spk[q][tid];
    }
    __syncthreads();
  }

  float* kvp = kv + (size_t)blk * 1024;
#pragma unroll
  for (int m = 0; m < 4; ++m) kvp[(k0 + 8*m)*32 + dd] = acc[m];
  if (tid < 32) ksum[(size_t)blk * 32 + tid] = ks;
}

// ---------- attn = (pq @ kv) / (pq @ ksum + eps) -> bf16  (BJT layout) ----------
__global__ __launch_bounds__(256) void k_attn(const __hip_bfloat16* __restrict__ pq,
                                              const float* __restrict__ kv,
                                              const float* __restrict__ ksum,
                                              __hip_bfloat16* __restrict__ attn) {
  __shared__ float psf[32][264];
  __shared__ float dens[32][8];
  int bj = blockIdx.y;
  int t0 = blockIdx.x * 32;
  int g0 = bj * 512 + t0;        // r' base row
  int tid = threadIdx.x, w = tid >> 6, l = tid & 63;
  int h = w*2 + (l >> 5), dd = l & 31;

  const float* kvp = kv + ((size_t)bj * 8 + h) * (DH_*DH_);
  float kvreg[32];
#pragma unroll
  for (int k = 0; k < 32; ++k) kvreg[k] = kvp[k*32 + dd];

  for (int tr = 0; tr < 32; ++tr)
    psf[tr][tid] = __bfloat162float(pq[(size_t)(g0 + tr) * D_ + tid]);
  __syncthreads();

  {
    int tr = tid & 31, hh = tid >> 5;
    const float* ksp = ksum + ((size_t)bj * 8 + hh) * DH_;
    float dsum = 0.f;
#pragma unroll
    for (int k = 0; k < 32; ++k) dsum = fmaf(psf[tr][hh*32 + k], ksp[k], dsum);
    dens[tr][hh] = dsum;
  }
  __syncthreads();

  for (int tr = 0; tr < 32; ++tr) {
    const float* pr = &psf[tr][h*32];
    float num = 0.f;
#pragma unroll
    for (int k = 0; k < 32; ++k) num = fmaf(pr[k], kvreg[k], num);
    float rden = __builtin_amdgcn_rcpf(dens[tr][h] + EPSF);
    attn[(size_t)(g0 + tr) * D_ + tid] = __float2bfloat16(num * rden);
  }
}

// ---------- u2 = LN(xs + sinh(|o|)/|o| * o): o row r', x row r ----------
__global__ __launch_bounds__(256) void k_u2(const __hip_bfloat16* __restrict__ o,
                                            const float* __restrict__ x,
                                            const float* __restrict__ g2,
                                            const float* __restrict__ beta2,
                                            __hip_bfloat16* __restrict__ u2) {
  int rp = blockIdx.x * 4 + (threadIdx.x >> 6);
  int l = threadIdx.x & 63;
  int r = rp_to_r(rp);
  const float* xr = x + (size_t)r * NP1;
  float ov[4], xs[4];
#pragma unroll
  for (int i = 0; i < 4; ++i) {
    ov[i] = __bfloat162float(o[(size_t)rp * D_ + l + 64*i]);
    xs[i] = xr[1 + l + 64*i];
  }
  float p2 = ov[0]*ov[0]+ov[1]*ov[1]+ov[2]*ov[2]+ov[3]*ov[3];
  float s2o = wave_sum(p2);
  float no = fmaxf(sqrtf(s2o), EPSF);
  float e = __expf(no);
  float c = (e - 1.0f/e) * 0.5f / no;
  float mi[4];
#pragma unroll
  for (int i = 0; i < 4; ++i) mi[i] = xs[i] + c * ov[i];
  float q1 = mi[0]+mi[1]+mi[2]+mi[3];
  float q2 = mi[0]*mi[0]+mi[1]*mi[1]+mi[2]*mi[2]+mi[3]*mi[3];
  float s1 = wave_sum(q1);
  float s2 = wave_sum(q2);
  float mean = s1 * (1.0f/256.0f);
  float var = s2 * (1.0f/256.0f) - mean*mean;
  float rstd = rsqrtf(var + 1e-5f);
#pragma unroll
  for (int i = 0; i < 4; ++i) {
    int cc = l + 64*i;
    u2[(size_t)rp * D_ + cc] = __float2bfloat16((mi[i]-mean)*rstd*g2[cc] + beta2[cc]);
  }
}

extern "C" void kernel_launch(void* const* d_in, const int* in_sizes, int n_in,
                              void* d_out, int out_size, void* d_ws, size_t ws_size,
                              hipStream_t stream) {
  const float* x     = (const float*)d_in[0];
  const float* g1    = (const float*)d_in[1];
  const float* beta1 = (const float*)d_in[2];
  const float* Wq    = (const float*)d_in[3];
  const float* Wk    = (const float*)d_in[4];
  const float* Wv    = (const float*)d_in[5];
  const float* Wo    = (const float*)d_in[6];
  const float* bq    = (const float*)d_in[7];
  const float* bk    = (const float*)d_in[8];
  const float* bv    = (const float*)d_in[9];
  const float* bo    = (const float*)d_in[10];
  const float* g2    = (const float*)d_in[11];
  const float* beta2 = (const float*)d_in[12];
  const float* W1    = (const float*)d_in[13];
  const float* bf1   = (const float*)d_in[14];
  const float* W2    = (const float*)d_in[15];
  const float* bf2   = (const float*)d_in[16];
  float* out = (float*)d_out;
  char* ws = (char*)d_ws;

  // ---- workspace layout (bytes) ----
  size_t off = 0;
  __hip_bfloat16* wqT = (__hip_bfloat16*)(ws + off); off += (size_t)D_*D_*2;
  __hip_bfloat16* wkT = (__hip_bfloat16*)(ws + off); off += (size_t)D_*D_*2;
  __hip_bfloat16* wvT = (__hip_bfloat16*)(ws + off); off += (size_t)D_*D_*2;
  __hip_bfloat16* woT = (__hip_bfloat16*)(ws + off); off += (size_t)D_*D_*2;
  __hip_bfloat16* w1T = (__hip_bfloat16*)(ws + off); off += (size_t)HID_*D_*2;
  __hip_bfloat16* w2T = (__hip_bfloat16*)(ws + off); off += (size_t)D_*HID_*2;
  float* kvb = (float*)(ws + off); off += (size_t)NBH*(DH_*DH_)*4;
  float* ksb = (float*)(ws + off); off += (size_t)NBH*DH_*4;
  off = (off + 255) & ~(size_t)255;
  __hip_bfloat16* tb = (__hip_bfloat16*)(ws + off); off += (size_t)R_*D_*2;
  __hip_bfloat16* qb = (__hip_bfloat16*)(ws + off); off += (size_t)R_*D_*2;
  __hip_bfloat16* kb = (__hip_bfloat16*)(ws + off); off += (size_t)R_*D_*2;
  __hip_bfloat16* vb = (__hip_bfloat16*)(ws + off); off += (size_t)R_*D_*2;
  __hip_bfloat16* hid = (__hip_bfloat16*)(ws + off); off += (size_t)(R_/2)*HID_*2;

  static bool attr_done = false;
  if (!attr_done) {
    hipFuncSetAttribute((const void*)k_gemm<1,0,256>,  hipFuncAttributeMaxDynamicSharedMemorySize, 131072);
    hipFuncSetAttribute((const void*)k_gemm<0,0,256>,  hipFuncAttributeMaxDynamicSharedMemorySize, 131072);
    hipFuncSetAttribute((const void*)k_gemm<2,0,256>,  hipFuncAttributeMaxDynamicSharedMemorySize, 131072);
    hipFuncSetAttribute((const void*)k_gemm<0,2,1024>, hipFuncAttributeMaxDynamicSharedMemorySize, 131072);
    attr_done = true;
  }

  dim3 tconv(32, 8);
  k_wconv<<<dim3(D_/32,  D_/32),  tconv, 0, stream>>>(Wq, wqT, D_,  D_);
  k_wconv<<<dim3(D_/32,  D_/32),  tconv, 0, stream>>>(Wk, wkT, D_,  D_);
  k_wconv<<<dim3(D_/32,  D_/32),  tconv, 0, stream>>>(Wv, wvT, D_,  D_);
  k_wconv<<<dim3(D_/32,  D_/32),  tconv, 0, stream>>>(Wo, woT, D_,  D_);
  k_wconv<<<dim3(HID_/32, D_/32), tconv, 0, stream>>>(W1, w1T, D_,  HID_);
  k_wconv<<<dim3(D_/32, HID_/32), tconv, 0, stream>>>(W2, w2T, HID_, D_);

  k_t<<<R_/4, 256, 0, stream>>>(x, g1, beta1, tb);      // tb in r' layout

  dim3 gqkv(D_/256, R_/256);                 // (1, 416)
  k_gemm<1,0,256><<<gqkv, 512, 131072, stream>>>(tb, wqT, bq, qb, R_, D_, 0);
  k_gemm<1,0,256><<<gqkv, 512, 131072, stream>>>(tb, wkT, bk, kb, R_, D_, 0);
  k_gemm<0,0,256><<<gqkv, 512, 131072, stream>>>(tb, wvT, bv, vb, R_, D_, 0);

  k_kv<<<NBH, 256, 0, stream>>>(kb, vb, kvb, ksb);
  k_attn<<<dim3(T_/32, NBJ), 256, 0, stream>>>(qb, kvb, ksb, kb);   // attn -> kb

  k_gemm<0,0,256><<<gqkv, 512, 131072, stream>>>(kb, woT, bo, vb, R_, D_, 0);  // o -> vb (r')
  k_u2<<<R_/4, 256, 0, stream>>>(vb, x, g2, beta2, tb);                        // u2 -> tb (r')

  const int Rc = R_ / 2;                     // 53248 rows per MLP chunk
  for (int c = 0; c < 2; ++c) {
    k_gemm<2,0,256><<<dim3(HID_/256, Rc/256), 512, 131072, stream>>>(
        tb + (size_t)c * Rc * D_, w1T, bf1, hid, Rc, HID_, 0);
    k_gemm<0,2,1024><<<dim3(1, Rc/256), 512, 131072, stream>>>(
        hid, w2T, bf2, out, Rc, D_, c * Rc);            // fused expmap0 -> out
  }
}

// Round 8
// 711.534 us; speedup vs baseline: 5.1025x; 1.0993x over previous
//
#include <hip/hip_runtime.h>
#include <hip/hip_bf16.h>
#include <math.h>

// LorentzTemporalBlock — bf16 MFMA GEMMs + analytically-simplified elementwise.
// B=8,T=512,J=26,D=256,H=8,DH=32,HID=1024. R = 106496 rows (= 416*256).
// Identities: t = LN(xs); u2 = LN(xs + sinh(|o|)/|o| * o)  (LN scale-invariance).
// R3: 8-phase 256x256 MFMA GEMM (T2+T3/T4+T5): 802 us.
// R5/R6: k_kv t-split partial variants — pathological write amplification
//     (mechanism unidentified); reverted to per-(bj,h) granularity in R7.
// R7: k_kv v5 (vectorized staging) 95 us — LDS-issue-bound (5 b32 : 4 FMA).
// R8: k_kv v6 — same skeleton; thread owns 4kx4d tile, q split across waves:
//     per q = 2 ds_read_b128 + 16 FMA (conflict-free, rows padded to 36 f32);
//     cross-wave reduce via LDS. QKV GEMMs fused into ONE dispatch
//     (grid (3,416) over contiguous wqT|wkT|wvT and qb|kb|vb; EPI=1 selects
//     bias/act/output by n0>>8) — A-tiles L2-shared, 2 fewer dispatches.

#define EPSF 1e-6f
#define B_ 8
#define T_ 512
#define J_ 26
#define D_ 256
#define H_ 8
#define DH_ 32
#define HID_ 1024
#define NP1 257
#define R_ (B_*T_*J_)    // 106496
#define NBJ (B_*J_)      // 208
#define NBH (NBJ*H_)     // 1664

typedef float  f32x4  __attribute__((ext_vector_type(4)));
typedef short  s16x8  __attribute__((ext_vector_type(8)));
typedef short  s16x4  __attribute__((ext_vector_type(4)));

// r' = (b*26+j)*512 + t  ->  r = (b*512+t)*26 + j   (wave-uniform div by const)
__device__ __forceinline__ int rp_to_r(int rp) {
  int bj = rp >> 9, t = rp & 511;
  int b = bj / 26, j = bj - 26 * b;
  return (b * 512 + t) * 26 + j;
}

// ---------- async global->LDS 16B (dst = uniform base + lane*16) ----------
__device__ __forceinline__ void async16(const void* g, void* l) {
  __builtin_amdgcn_global_load_lds(
      (const __attribute__((address_space(1))) unsigned int*)g,
      (__attribute__((address_space(3))) unsigned int*)l, 16, 0, 0);
}

// ---------- wave-wide (64 lane) sum, result in all lanes ----------
__device__ __forceinline__ float wave_sum(float v) {
#pragma unroll
  for (int m = 32; m; m >>= 1) v += __shfl_xor(v, m, 64);
  return v;
}

// ---------- weight transpose+convert: W fp32 [K][N] -> Wt bf16 [N][K] ----------
__global__ __launch_bounds__(256) void k_wconv(const float* __restrict__ W,
                                               __hip_bfloat16* __restrict__ Wt,
                                               int K, int N) {
  __shared__ float tile[32][33];
  int n0 = blockIdx.x * 32, k0 = blockIdx.y * 32;
  int tx = threadIdx.x, ty = threadIdx.y;   // (32,8)
#pragma unroll
  for (int i = ty; i < 32; i += 8) tile[i][tx] = W[(size_t)(k0 + i) * N + n0 + tx];
  __syncthreads();
#pragma unroll
  for (int i = ty; i < 32; i += 8)
    Wt[(size_t)(n0 + i) * K + k0 + tx] = __float2bfloat16(tile[tx][i]);
}

// ---------- t = LN(xs): read x row r, write t row r'  (wave-per-row) ----------
__global__ __launch_bounds__(256) void k_t(const float* __restrict__ x,
                                           const float* __restrict__ g1,
                                           const float* __restrict__ beta1,
                                           __hip_bfloat16* __restrict__ t) {
  int rp = blockIdx.x * 4 + (threadIdx.x >> 6);
  int l = threadIdx.x & 63;
  int r = rp_to_r(rp);
  const float* xr = x + (size_t)r * NP1;
  float xs[4];
#pragma unroll
  for (int i = 0; i < 4; ++i) xs[i] = xr[1 + l + 64*i];
  float p1 = xs[0]+xs[1]+xs[2]+xs[3];
  float p2 = xs[0]*xs[0]+xs[1]*xs[1]+xs[2]*xs[2]+xs[3]*xs[3];
  float s1 = wave_sum(p1);
  float s2 = wave_sum(p2);
  float mean = s1 * (1.0f/256.0f);
  float var = s2 * (1.0f/256.0f) - mean*mean;
  float rstd = rsqrtf(var + 1e-5f);
#pragma unroll
  for (int i = 0; i < 4; ++i) {
    int c = l + 64*i;
    t[(size_t)rp * D_ + c] = __float2bfloat16((xs[i]-mean)*rstd*g1[c] + beta1[c]);
  }
}

// ---------- 256x256 8-phase bf16 MFMA GEMM: C = act(A @ Bt^T + bias) ----------
// EPI 0: bf16 C store (ACT applies).
// EPI 1: fused QKV — Bt rows [0,768) = wq|wk|wv, Cout = qb|kb|vb (contiguous,
//        stride R_*256 shorts); bi = n0>>8 picks bias/act (elu+1 for q,k).
// EPI 2: fused expmap0 -> out (N=256, grid.x=1): row-norm via quad-shuffle +
//        LDS cross-wave reduce; stores to out[rp_to_r(mOff+row)*257].
#define PHASE(BUF, MH, NH, GIDX, DO_VM) {                                      \
    s16x8 af_[4][2]; s16x8 bf_[2][2];                                          \
    const char* ab_ = lds + ((BUF)*2+(MH))*16384;                              \
    const char* bb_ = lds + 65536 + ((BUF)*2+(NH))*16384;                      \
    _Pragma("unroll") for (int f_ = 0; f_ < 4; ++f_)                           \
      _Pragma("unroll") for (int ks_ = 0; ks_ < 2; ++ks_)                      \
        af_[f_][ks_] = *(const s16x8*)(ab_ + aoffs[f_][ks_]);                  \
    _Pragma("unroll") for (int ni_ = 0; ni_ < 2; ++ni_)                        \
      _Pragma("unroll") for (int ks_ = 0; ks_ < 2; ++ks_)                      \
        bf_[ni_][ks_] = *(const s16x8*)(bb_ + boffs[ni_][ks_]);                \
    STAGE_HALF((GIDX) + 6);                                                    \
    if (DO_VM) asm volatile("s_waitcnt vmcnt(4)" ::: "memory");                \
    asm volatile("s_barrier" ::: "memory");                                    \
    __builtin_amdgcn_sched_barrier(0);                                         \
    __builtin_amdgcn_s_setprio(1);                                             \
    _Pragma("unroll") for (int ks_ = 0; ks_ < 2; ++ks_)                        \
      _Pragma("unroll") for (int f_ = 0; f_ < 4; ++f_)                         \
        _Pragma("unroll") for (int ni_ = 0; ni_ < 2; ++ni_)                    \
          acc[(MH)*4+f_][(NH)*2+ni_] = __builtin_amdgcn_mfma_f32_16x16x32_bf16(\
              bf_[ni_][ks_], af_[f_][ks_], acc[(MH)*4+f_][(NH)*2+ni_], 0,0,0); \
    __builtin_amdgcn_s_setprio(0);                                             \
    asm volatile("s_barrier" ::: "memory");                                    \
  }

template<int ACT, int EPI, int KDIM>
__global__ __launch_bounds__(512, 2) void k_gemm(const __hip_bfloat16* __restrict__ A,
                                                 const __hip_bfloat16* __restrict__ Bt,
                                                 const float* __restrict__ bias,
                                                 const float* __restrict__ bias2,
                                                 const float* __restrict__ bias3,
                                                 void* __restrict__ Cout,
                                                 int M, int N, int mOff) {
  extern __shared__ char lds[];
  constexpr int NKT = KDIM / 64;
  int tid = threadIdx.x;
  int w = tid >> 6, l = tid & 63;
  int wr = w >> 2, wc = w & 3;
  int ml = l & 15, quad = l >> 4;
  int n0 = blockIdx.x * 256, m0 = blockIdx.y * 256;

  const short* Ag = (const short*)A + (size_t)m0 * KDIM;
  const short* Bg = (const short*)Bt + (size_t)n0 * KDIM;

  int srow = w*8 + (l >> 3);
  int scol = (((l & 7) ^ ((l >> 3) & 7)) * 8);

  auto STAGE_HALF = [&](int n) {
    if (n >= 4*NKT) return;
    int kt = n >> 2;
    int isB = n & 1, h = (n >> 1) & 1, buf = kt & 1;
    const short* src = isB ? Bg : Ag;
    const short* g0 = src + (size_t)(h*128 + srow) * KDIM + kt*64 + scol;
    char* dst = lds + isB*65536 + (buf*2 + h)*16384 + w*1024;
    async16(g0, dst);
    async16(g0 + (size_t)64 * KDIM, dst + 8192);
  };

  int aoffs[4][2], boffs[2][2];
#pragma unroll
  for (int f = 0; f < 4; ++f) {
    int r = wr*64 + f*16 + ml;
#pragma unroll
    for (int ks = 0; ks < 2; ++ks)
      aoffs[f][ks] = (r*128 + ks*64 + quad*16) ^ ((ml & 7) << 4);
  }
#pragma unroll
  for (int ni = 0; ni < 2; ++ni) {
    int rb = wc*32 + ni*16 + ml;
#pragma unroll
    for (int ks = 0; ks < 2; ++ks)
      boffs[ni][ks] = (rb*128 + ks*64 + quad*16) ^ ((ml & 7) << 4);
  }

  f32x4 acc[8][4];
#pragma unroll
  for (int i = 0; i < 8; ++i)
#pragma unroll
    for (int j = 0; j < 4; ++j) acc[i][j] = {0.f, 0.f, 0.f, 0.f};

#pragma unroll
  for (int n = 0; n < 6; ++n) STAGE_HALF(n);
  asm volatile("s_waitcnt vmcnt(4)" ::: "memory");
  asm volatile("s_barrier" ::: "memory");

  for (int cc = 0; cc < NKT/2; ++cc) {
    int g0 = cc * 8;
    PHASE(0, 0, 0, g0+0, 0)
    PHASE(0, 0, 1, g0+1, 0)
    PHASE(0, 1, 0, g0+2, 0)
    PHASE(0, 1, 1, g0+3, 1)
    PHASE(1, 0, 0, g0+4, 0)
    PHASE(1, 0, 1, g0+5, 0)
    PHASE(1, 1, 0, g0+6, 0)
    PHASE(1, 1, 1, g0+7, 1)
  }

  if (EPI == 0 || EPI == 1) {
    int bi = n0 >> 8;
    const float* bsel = (EPI == 1) ? (bi == 0 ? bias : bi == 1 ? bias2 : bias3)
                                   : bias;
    int doElu = (EPI == 1) ? (bi < 2) : (ACT == 1);
#pragma unroll
    for (int mi = 0; mi < 8; ++mi) {
      size_t row = (size_t)(m0 + (mi>>2)*128 + wr*64 + (mi&3)*16 + ml);
#pragma unroll
      for (int nj = 0; nj < 4; ++nj) {
        int col = n0 + (nj>>1)*128 + wc*32 + (nj&1)*16 + quad*4;
        int colL = col & 255;
        f32x4 bj = *(const f32x4*)&bsel[(EPI == 1) ? colL : col];
        f32x4 v = acc[mi][nj] + bj;
        if (doElu) {
#pragma unroll
          for (int e = 0; e < 4; ++e) v[e] = (v[e] > 0.0f) ? v[e] + 1.0f : __expf(v[e]);
        } else if (EPI == 0 && ACT == 2) {
#pragma unroll
          for (int e = 0; e < 4; ++e) {
            float vv = v[e], v2 = vv * vv;
            float ex = __expf(vv * fmaf(v2, -0.0713548327f, -1.5957691216f));
            v[e] = vv * __builtin_amdgcn_rcpf(1.0f + ex);
          }
        }
        s16x4 sv;
#pragma unroll
        for (int e = 0; e < 4; ++e) {
          __hip_bfloat16 b = __float2bfloat16(v[e]);
          sv[e] = *(short*)&b;
        }
        if (EPI == 1) {
          short* cb = (short*)Cout + (size_t)bi * R_ * 256;
          *(s16x4*)&cb[row * 256 + colL] = sv;
        } else {
          *(s16x4*)&((__hip_bfloat16*)Cout)[row * N + col] = sv;
        }
      }
    }
  } else {
    // EPI==2: out = expmap0(acc + bias), rows mapped r' -> r. N == 256.
    float* out = (float*)Cout;
    float* red = (float*)lds;            // [wr][wc][mi][ml] = 2*4*8*16 floats
    f32x4 bj4[4];
#pragma unroll
    for (int nj = 0; nj < 4; ++nj)
      bj4[nj] = *(const f32x4*)&bias[(nj>>1)*128 + wc*32 + (nj&1)*16 + quad*4];
    float n2[8];
#pragma unroll
    for (int mi = 0; mi < 8; ++mi) {
      float p = 0.f;
#pragma unroll
      for (int nj = 0; nj < 4; ++nj)
#pragma unroll
        for (int e = 0; e < 4; ++e) {
          float f = acc[mi][nj][e] + bj4[nj][e];
          p = fmaf(f, f, p);
        }
      p += __shfl_xor(p, 16, 64);        // sum over quad
      p += __shfl_xor(p, 32, 64);
      n2[mi] = p;
    }
    __syncthreads();                     // main-loop LDS fully retired
    if (quad == 0) {
#pragma unroll
      for (int mi = 0; mi < 8; ++mi)
        red[((wr*4 + wc)*8 + mi)*16 + ml] = n2[mi];
    }
    __syncthreads();
#pragma unroll
    for (int mi = 0; mi < 8; ++mi) {
      float s = 0.f;
#pragma unroll
      for (int w2 = 0; w2 < 4; ++w2)
        s += red[((wr*4 + w2)*8 + mi)*16 + ml];
      n2[mi] = s;
    }
#pragma unroll
    for (int mi = 0; mi < 8; ++mi) {
      int rowp = m0 + (mi>>2)*128 + wr*64 + (mi&3)*16 + ml;
      int r = rp_to_r(mOff + rowp);
      float* orow = out + (size_t)r * NP1;
      float n = fmaxf(sqrtf(n2[mi]), EPSF);
      float e = __expf(n);
      float ie = 1.0f / e;
      float sc = (e - ie) * 0.5f / n;    // sinh(n)/n
      if (wc == 0 && quad == 0) orow[0] = (e + ie) * 0.5f;
#pragma unroll
      for (int nj = 0; nj < 4; ++nj) {
        int col = (nj>>1)*128 + wc*32 + (nj&1)*16 + quad*4;
#pragma unroll
        for (int e2 = 0; e2 < 4; ++e2)
          orow[1 + col + e2] = sc * (acc[mi][nj][e2] + bj4[nj][e2]);
      }
    }
  }
}

// ---------- kv + ksum per (bj,h) — v6: 4x4 tile/thread, q split by wave ----------
// grid NBH (1664 blocks), 256 threads = 4 waves. BJT rows (bj*512+t),
// cols [h*32,+32). 16 chunks of 32 t: staging as v5 (8B s16x4 -> cvt ->
// f32 LDS, rows padded to 36 floats: conflict-free b128 writes AND reads).
// Wave w computes q = w*8..w*8+7 per chunk; lane (kg=l>>3, dg=l&7) owns
// acc[m][n] = sum_q pk[q][kg*4+m]*v[q][dg*4+n]: per q = 2 b128 + 16 FMA.
// End: 4-wave partial reduce through LDS (staging region, dead by then).
__global__ __launch_bounds__(256) void k_kv(const __hip_bfloat16* __restrict__ pk,
                                            const __hip_bfloat16* __restrict__ v,
                                            float* __restrict__ kv,
                                            float* __restrict__ ksum) {
  __shared__ float sbuf[4096];        // staging: spk [32][36] @0, sv [32][36] @1152
  __shared__ float sks[4][32];        // red: sbuf[tid*16 + ..] (16KB, aliased)
  int blk = blockIdx.x;
  int h = blk & 7, bj = blk >> 3;
  int tid = threadIdx.x;
  int w = tid >> 6, l = tid & 63;
  int row = tid >> 3, cg = tid & 7;   // staging coords
  int kg = l >> 3, dg = l & 7;        // compute coords

  float* spk = sbuf;
  float* sv  = sbuf + 1152;

  const short* pkg = (const short*)pk + (size_t)bj*512*256 + h*32 + cg*4;
  const short* vg  = (const short*)v  + (size_t)bj*512*256 + h*32 + cg*4;

  s16x4 rp_, rv_;
  auto GLOAD = [&](int c) {
    size_t off = (size_t)(c*32 + row) * 256;
    rp_ = *(const s16x4*)(pkg + off);
    rv_ = *(const s16x4*)(vg + off);
  };

  f32x4 acc[4] = {{0,0,0,0},{0,0,0,0},{0,0,0,0},{0,0,0,0}};  // [m] over n
  float ks[4] = {0.f, 0.f, 0.f, 0.f};

  GLOAD(0);
  for (int c = 0; c < 16; ++c) {
    f32x4 pf, vf;
#pragma unroll
    for (int e = 0; e < 4; ++e) {
      pf[e] = __uint_as_float(((unsigned)(unsigned short)rp_[e]) << 16);
      vf[e] = __uint_as_float(((unsigned)(unsigned short)rv_[e]) << 16);
    }
    *(f32x4*)&spk[row*36 + cg*4] = pf;
    *(f32x4*)&sv [row*36 + cg*4] = vf;
    __syncthreads();
    if (c < 15) GLOAD(c + 1);           // in flight during compute
#pragma unroll
    for (int qq = 0; qq < 8; ++qq) {
      int q = w*8 + qq;
      f32x4 pq4 = *(const f32x4*)&spk[q*36 + kg*4];
      f32x4 vq4 = *(const f32x4*)&sv [q*36 + dg*4];
#pragma unroll
      for (int m = 0; m < 4; ++m) {
#pragma unroll
        for (int n = 0; n < 4; ++n) acc[m][n] = fmaf(pq4[m], vq4[n], acc[m][n]);
        ks[m] += pq4[m];
      }
    }
    __syncthreads();
  }

  // cross-wave reduce of acc (4 q-partials) through LDS
#pragma unroll
  for (int m = 0; m < 4; ++m) *(f32x4*)&sbuf[tid*16 + m*4] = acc[m];
  if (dg == 0) {
#pragma unroll
    for (int m = 0; m < 4; ++m) sks[w][kg*4 + m] = ks[m];
  }
  __syncthreads();
  {
    int lo = tid & 63, m = tid >> 6;
    f32x4 s = {0.f, 0.f, 0.f, 0.f};
#pragma unroll
    for (int ww = 0; ww < 4; ++ww) s += *(const f32x4*)&sbuf[(ww*64 + lo)*16 + m*4];
    int kgo = lo >> 3, dgo = lo & 7;
    *(f32x4*)&kv[(size_t)blk*1024 + (size_t)(kgo*4 + m)*32 + dgo*4] = s;
  }
  if (tid < 32)
    ksum[(size_t)blk*32 + tid] = sks[0][tid] + sks[1][tid] + sks[2][tid] + sks[3][tid];
}

// ---------- attn = (pq @ kv) / (pq @ ksum + eps) -> bf16  (BJT layout) ----------
__global__ __launch_bounds__(256) void k_attn(const __hip_bfloat16* __restrict__ pq,
                                              const float* __restrict__ kv,
                                              const float* __restrict__ ksum,
                                              __hip_bfloat16* __restrict__ attn) {
  __shared__ float psf[32][264];
  __shared__ float dens[32][8];
  int bj = blockIdx.y;
  int t0 = blockIdx.x * 32;
  int g0 = bj * 512 + t0;        // r' base row
  int tid = threadIdx.x, w = tid >> 6, l = tid & 63;
  int h = w*2 + (l >> 5), dd = l & 31;

  const float* kvp = kv + ((size_t)bj * 8 + h) * (DH_*DH_);
  float kvreg[32];
#pragma unroll
  for (int k = 0; k < 32; ++k) kvreg[k] = kvp[k*32 + dd];

  for (int tr = 0; tr < 32; ++tr)
    psf[tr][tid] = __bfloat162float(pq[(size_t)(g0 + tr) * D_ + tid]);
  __syncthreads();

  {
    int tr = tid & 31, hh = tid >> 5;
    const float* ksp = ksum + ((size_t)bj * 8 + hh) * DH_;
    float dsum = 0.f;
#pragma unroll
    for (int k = 0; k < 32; ++k) dsum = fmaf(psf[tr][hh*32 + k], ksp[k], dsum);
    dens[tr][hh] = dsum;
  }
  __syncthreads();

  for (int tr = 0; tr < 32; ++tr) {
    const float* pr = &psf[tr][h*32];
    float num = 0.f;
#pragma unroll
    for (int k = 0; k < 32; ++k) num = fmaf(pr[k], kvreg[k], num);
    float rden = __builtin_amdgcn_rcpf(dens[tr][h] + EPSF);
    attn[(size_t)(g0 + tr) * D_ + tid] = __float2bfloat16(num * rden);
  }
}

// ---------- u2 = LN(xs + sinh(|o|)/|o| * o): o row r', x row r ----------
__global__ __launch_bounds__(256) void k_u2(const __hip_bfloat16* __restrict__ o,
                                            const float* __restrict__ x,
                                            const float* __restrict__ g2,
                                            const float* __restrict__ beta2,
                                            __hip_bfloat16* __restrict__ u2) {
  int rp = blockIdx.x * 4 + (threadIdx.x >> 6);
  int l = threadIdx.x & 63;
  int r = rp_to_r(rp);
  const float* xr = x + (size_t)r * NP1;
  float ov[4], xs[4];
#pragma unroll
  for (int i = 0; i < 4; ++i) {
    ov[i] = __bfloat162float(o[(size_t)rp * D_ + l + 64*i]);
    xs[i] = xr[1 + l + 64*i];
  }
  float p2 = ov[0]*ov[0]+ov[1]*ov[1]+ov[2]*ov[2]+ov[3]*ov[3];
  float s2o = wave_sum(p2);
  float no = fmaxf(sqrtf(s2o), EPSF);
  float e = __expf(no);
  float c = (e - 1.0f/e) * 0.5f / no;
  float mi[4];
#pragma unroll
  for (int i = 0; i < 4; ++i) mi[i] = xs[i] + c * ov[i];
  float q1 = mi[0]+mi[1]+mi[2]+mi[3];
  float q2 = mi[0]*mi[0]+mi[1]*mi[1]+mi[2]*mi[2]+mi[3]*mi[3];
  float s1 = wave_sum(q1);
  float s2 = wave_sum(q2);
  float mean = s1 * (1.0f/256.0f);
  float var = s2 * (1.0f/256.0f) - mean*mean;
  float rstd = rsqrtf(var + 1e-5f);
#pragma unroll
  for (int i = 0; i < 4; ++i) {
    int cc = l + 64*i;
    u2[(size_t)rp * D_ + cc] = __float2bfloat16((mi[i]-mean)*rstd*g2[cc] + beta2[cc]);
  }
}

extern "C" void kernel_launch(void* const* d_in, const int* in_sizes, int n_in,
                              void* d_out, int out_size, void* d_ws, size_t ws_size,
                              hipStream_t stream) {
  const float* x     = (const float*)d_in[0];
  const float* g1    = (const float*)d_in[1];
  const float* beta1 = (const float*)d_in[2];
  const float* Wq    = (const float*)d_in[3];
  const float* Wk    = (const float*)d_in[4];
  const float* Wv    = (const float*)d_in[5];
  const float* Wo    = (const float*)d_in[6];
  const float* bq    = (const float*)d_in[7];
  const float* bk    = (const float*)d_in[8];
  const float* bv    = (const float*)d_in[9];
  const float* bo    = (const float*)d_in[10];
  const float* g2    = (const float*)d_in[11];
  const float* beta2 = (const float*)d_in[12];
  const float* W1    = (const float*)d_in[13];
  const float* bf1   = (const float*)d_in[14];
  const float* W2    = (const float*)d_in[15];
  const float* bf2   = (const float*)d_in[16];
  float* out = (float*)d_out;
  char* ws = (char*)d_ws;

  // ---- workspace layout (bytes) ----
  size_t off = 0;
  __hip_bfloat16* wqT = (__hip_bfloat16*)(ws + off); off += (size_t)D_*D_*2;   // wq|wk|wv
  __hip_bfloat16* wkT = (__hip_bfloat16*)(ws + off); off += (size_t)D_*D_*2;   //  contiguous
  __hip_bfloat16* wvT = (__hip_bfloat16*)(ws + off); off += (size_t)D_*D_*2;
  __hip_bfloat16* woT = (__hip_bfloat16*)(ws + off); off += (size_t)D_*D_*2;
  __hip_bfloat16* w1T = (__hip_bfloat16*)(ws + off); off += (size_t)HID_*D_*2;
  __hip_bfloat16* w2T = (__hip_bfloat16*)(ws + off); off += (size_t)D_*HID_*2;
  float* kvb = (float*)(ws + off); off += (size_t)NBH*(DH_*DH_)*4;
  float* ksb = (float*)(ws + off); off += (size_t)NBH*DH_*4;
  off = (off + 255) & ~(size_t)255;
  __hip_bfloat16* tb = (__hip_bfloat16*)(ws + off); off += (size_t)R_*D_*2;
  __hip_bfloat16* qb = (__hip_bfloat16*)(ws + off); off += (size_t)R_*D_*2;    // qb|kb|vb
  __hip_bfloat16* kb = (__hip_bfloat16*)(ws + off); off += (size_t)R_*D_*2;    //  contiguous
  __hip_bfloat16* vb = (__hip_bfloat16*)(ws + off); off += (size_t)R_*D_*2;
  __hip_bfloat16* hid = (__hip_bfloat16*)(ws + off); off += (size_t)(R_/2)*HID_*2;

  static bool attr_done = false;
  if (!attr_done) {
    hipFuncSetAttribute((const void*)k_gemm<0,1,256>,  hipFuncAttributeMaxDynamicSharedMemorySize, 131072);
    hipFuncSetAttribute((const void*)k_gemm<0,0,256>,  hipFuncAttributeMaxDynamicSharedMemorySize, 131072);
    hipFuncSetAttribute((const void*)k_gemm<2,0,256>,  hipFuncAttributeMaxDynamicSharedMemorySize, 131072);
    hipFuncSetAttribute((const void*)k_gemm<0,2,1024>, hipFuncAttributeMaxDynamicSharedMemorySize, 131072);
    attr_done = true;
  }

  dim3 tconv(32, 8);
  k_wconv<<<dim3(D_/32,  D_/32),  tconv, 0, stream>>>(Wq, wqT, D_,  D_);
  k_wconv<<<dim3(D_/32,  D_/32),  tconv, 0, stream>>>(Wk, wkT, D_,  D_);
  k_wconv<<<dim3(D_/32,  D_/32),  tconv, 0, stream>>>(Wv, wvT, D_,  D_);
  k_wconv<<<dim3(D_/32,  D_/32),  tconv, 0, stream>>>(Wo, woT, D_,  D_);
  k_wconv<<<dim3(HID_/32, D_/32), tconv, 0, stream>>>(W1, w1T, D_,  HID_);
  k_wconv<<<dim3(D_/32, HID_/32), tconv, 0, stream>>>(W2, w2T, HID_, D_);

  k_t<<<R_/4, 256, 0, stream>>>(x, g1, beta1, tb);      // tb in r' layout

  // fused QKV: N=768 over contiguous weights/outputs, one dispatch
  k_gemm<0,1,256><<<dim3(3, R_/256), 512, 131072, stream>>>(
      tb, wqT, bq, bk, bv, qb, R_, 256, 0);

  k_kv<<<NBH, 256, 0, stream>>>(kb, vb, kvb, ksb);
  k_attn<<<dim3(T_/32, NBJ), 256, 0, stream>>>(qb, kvb, ksb, kb);   // attn -> kb

  k_gemm<0,0,256><<<dim3(1, R_/256), 512, 131072, stream>>>(
      kb, woT, bo, nullptr, nullptr, vb, R_, D_, 0);                // o -> vb (r')
  k_u2<<<R_/4, 256, 0, stream>>>(vb, x, g2, beta2, tb);             // u2 -> tb (r')

  const int Rc = R_ / 2;                     // 53248 rows per MLP chunk
  for (int c = 0; c < 2; ++c) {
    k_gemm<2,0,256><<<dim3(HID_/256, Rc/256), 512, 131072, stream>>>(
        tb + (size_t)c * Rc * D_, w1T, bf1, nullptr, nullptr, hid, Rc, HID_, 0);
    k_gemm<0,2,1024><<<dim3(1, Rc/256), 512, 131072, stream>>>(
        hid, w2T, bf2, nullptr, nullptr, out, Rc, D_, c * Rc);      // expmap0 -> out
  }
}